// Round 2
// baseline (188.465 us; speedup 1.0000x reference)
//
#include <hip/hip_runtime.h>
#include <math.h>

// Problem constants: B=8, D=8 (channels), H=256, W=256, M=256
#define HWPIX 65536   // 256*256
#define NMATCH 256
#define THETA_LEN 169
#define TPK_STRIDE 128          // u32 per match in packed-theta workspace
#define TPK_BYTES (NMATCH * TPK_STRIDE * 4)

// NOTE: __fp16 (not _Float16) — this is the element type of
// __builtin_amdgcn_cvt_pkrtz's return and __builtin_amdgcn_fdot2's operands.
typedef __fp16 half2v __attribute__((ext_vector_type(2)));

// tanh-approx GELU in sigmoid form on HW transcendentals (unchanged, verified):
//   gelu(x) ~= x * sigmoid(1.5957691x + 0.0713548x^3)
__device__ __forceinline__ float gelu_fast(float v) {
    float t = fmaf(v * v, 0.10294323f, 2.3022082f);
    float e = __builtin_amdgcn_exp2f(-v * t);
    float r = __builtin_amdgcn_rcpf(1.0f + e);
    return v * r;
}

__device__ __forceinline__ half2v as_h2(uint32_t u) {
    union { uint32_t u; half2v h; } c; c.u = u; return c.h;
}
__device__ __forceinline__ float as_f32(uint32_t u) {
    union { uint32_t u; float f; } c; c.u = u; return c.f;
}

// ---------------------------------------------------------------------------
// Pre-kernel: pack theta (fp32) into per-match fp16 channel-pair weights +
// fp32 biases. Layout per match (u32 indices):
//   [0..39]  L0 weights: o*5+k ; k=0..3 -> (th[o*10+2k], th[o*10+2k+1]),
//                                 k=4   -> (th[o*10+8], th[o*10+9])  (rel pair)
//   [40..47] b0 = th[80+o]      (fp32 bits)
//   [48..79] L1 weights: o*4+k -> (th[88+o*8+2k], th[88+o*8+2k+1])
//   [80..87] b1 = th[152+o]
//   [88..91] L2 weights: k -> (th[160+2k], th[160+2k+1])
//   [92]     b2 = th[168]
// ---------------------------------------------------------------------------
__global__ __launch_bounds__(96) void pack_theta(
    const float* __restrict__ theta, uint32_t* __restrict__ tpk)
{
    const int m = blockIdx.x;
    const int t = threadIdx.x;
    const float* __restrict__ th = theta + m * THETA_LEN;
    uint32_t* __restrict__ o = tpk + m * TPK_STRIDE;

    float a = 0.f, b = 0.f;
    bool isPack = true;
    if (t < 40) {
        int oo = t / 5, k = t % 5;
        if (k < 4) { a = th[oo * 10 + 2 * k]; b = th[oo * 10 + 2 * k + 1]; }
        else       { a = th[oo * 10 + 8];     b = th[oo * 10 + 9]; }
    } else if (t < 48) { isPack = false; a = th[80 + (t - 40)]; }
    else if (t < 80) {
        int oo = (t - 48) / 4, k = (t - 48) % 4;
        a = th[88 + oo * 8 + 2 * k]; b = th[88 + oo * 8 + 2 * k + 1];
    } else if (t < 88) { isPack = false; a = th[152 + (t - 80)]; }
    else if (t < 92) { int k = t - 88; a = th[160 + 2 * k]; b = th[160 + 2 * k + 1]; }
    else if (t == 92) { isPack = false; a = th[168]; }
    else return;

    uint32_t r;
    if (isPack) {
        // RTZ pack matches the main kernel's activation conversion path; for
        // weights the <1e-3 rounding is within test tolerance either way.
        half2v h = __builtin_amdgcn_cvt_pkrtz(a, b);
        union { half2v h; uint32_t u; } c; c.h = h; r = c.u;
    } else {
        union { float f; uint32_t u; } c; c.f = a; r = c.u;
    }
    o[t] = r;
}

// ---------------------------------------------------------------------------
// Main kernel (fp16-dot2 path): matmuls via v_dot2_f32_f16 (2 MACs/instr,
// fp32 accumulate), weights wave-uniform from packed workspace (s_load).
// ---------------------------------------------------------------------------
__global__ __launch_bounds__(256) void dmh_kernel_dot2(
    const float* __restrict__ E,        // (8, 8, 256, 256)
    const uint32_t* __restrict__ tpk,   // packed theta (workspace)
    const float* __restrict__ centers,  // (256, 2)
    const int*   __restrict__ bidx,     // (256,)
    float* __restrict__ out)            // (256, 256, 256)
{
    const int m    = blockIdx.x >> 6;
    const int tile = blockIdx.x & 63;
    const int p0   = tile * 1024 + threadIdx.x * 4;

    const uint32_t* __restrict__ tp = tpk + m * TPK_STRIDE;   // uniform -> SGPR
    const float cx = centers[2 * m];
    const float cy = centers[2 * m + 1];
    const int   b  = bidx[m];
    const float* __restrict__ Eb = E + (size_t)b * (8 * HWPIX) + p0;

    const int h = p0 >> 8;
    const int w = p0 & 255;   // multiple of 4 -> 4 pixels share h

    // Inputs packed as channel-pairs: xp[cp][j], cp=0..3 E pairs, cp=4 = (rx,ry)
    half2v xp[5][4];
    #pragma unroll
    for (int cp = 0; cp < 4; ++cp) {
        const float4 v0 = *(const float4*)(Eb + (size_t)(2 * cp) * HWPIX);
        const float4 v1 = *(const float4*)(Eb + (size_t)(2 * cp + 1) * HWPIX);
        xp[cp][0] = __builtin_amdgcn_cvt_pkrtz(v0.x, v1.x);
        xp[cp][1] = __builtin_amdgcn_cvt_pkrtz(v0.y, v1.y);
        xp[cp][2] = __builtin_amdgcn_cvt_pkrtz(v0.z, v1.z);
        xp[cp][3] = __builtin_amdgcn_cvt_pkrtz(v0.w, v1.w);
    }
    const float ry = (h + 0.5f) * (1.0f / 256.0f) - cy;
    #pragma unroll
    for (int j = 0; j < 4; ++j) {
        const float rx = (w + j + 0.5f) * (1.0f / 256.0f) - cx;
        xp[4][j] = __builtin_amdgcn_cvt_pkrtz(rx, ry);
    }

    // Layer 0: 10 -> 8 (5 dot2 per output-pixel)
    float yv[8][4];
    #pragma unroll
    for (int o = 0; o < 8; ++o) {
        const float bias = as_f32(tp[40 + o]);
        float a[4] = {bias, bias, bias, bias};
        #pragma unroll
        for (int k = 0; k < 5; ++k) {
            const half2v wv = as_h2(tp[o * 5 + k]);   // SGPR operand
            #pragma unroll
            for (int j = 0; j < 4; ++j)
                a[j] = __builtin_amdgcn_fdot2(wv, xp[k][j], a[j], false);
        }
        #pragma unroll
        for (int j = 0; j < 4; ++j) yv[o][j] = gelu_fast(a[j]);
    }
    half2v yp[4][4];
    #pragma unroll
    for (int cp = 0; cp < 4; ++cp)
        #pragma unroll
        for (int j = 0; j < 4; ++j)
            yp[cp][j] = __builtin_amdgcn_cvt_pkrtz(yv[2 * cp][j], yv[2 * cp + 1][j]);

    // Layer 1: 8 -> 8 (4 dot2 per output-pixel)
    float zv[8][4];
    #pragma unroll
    for (int o = 0; o < 8; ++o) {
        const float bias = as_f32(tp[80 + o]);
        float a[4] = {bias, bias, bias, bias};
        #pragma unroll
        for (int k = 0; k < 4; ++k) {
            const half2v wv = as_h2(tp[48 + o * 4 + k]);
            #pragma unroll
            for (int j = 0; j < 4; ++j)
                a[j] = __builtin_amdgcn_fdot2(wv, yp[k][j], a[j], false);
        }
        #pragma unroll
        for (int j = 0; j < 4; ++j) zv[o][j] = gelu_fast(a[j]);
    }
    half2v zp[4][4];
    #pragma unroll
    for (int cp = 0; cp < 4; ++cp)
        #pragma unroll
        for (int j = 0; j < 4; ++j)
            zp[cp][j] = __builtin_amdgcn_cvt_pkrtz(zv[2 * cp][j], zv[2 * cp + 1][j]);

    // Layer 2: 8 -> 1
    const float b2 = as_f32(tp[92]);
    float r[4] = {b2, b2, b2, b2};
    #pragma unroll
    for (int k = 0; k < 4; ++k) {
        const half2v wv = as_h2(tp[88 + k]);
        #pragma unroll
        for (int j = 0; j < 4; ++j)
            r[j] = __builtin_amdgcn_fdot2(wv, zp[k][j], r[j], false);
    }

    float4 o4;
    o4.x = r[0]; o4.y = r[1]; o4.z = r[2]; o4.w = r[3];
    *(float4*)(out + (size_t)m * HWPIX + p0) = o4;
}

// ---------------------------------------------------------------------------
// Fallback: previous verified fp32 kernel (used only if workspace too small).
// ---------------------------------------------------------------------------
__global__ __launch_bounds__(256) void dmh_kernel_f32(
    const float* __restrict__ E,
    const float* __restrict__ theta,
    const float* __restrict__ centers,
    const int*   __restrict__ bidx,
    float* __restrict__ out)
{
    const int m    = blockIdx.x >> 6;
    const int tile = blockIdx.x & 63;
    const int p0   = tile * 1024 + threadIdx.x * 4;

    const float* __restrict__ th = theta + m * THETA_LEN;
    const float cx = centers[2 * m];
    const float cy = centers[2 * m + 1];
    const int   b  = bidx[m];
    const float* __restrict__ Eb = E + (size_t)b * (8 * HWPIX) + p0;

    const int h = p0 >> 8;
    const int w = p0 & 255;

    float x[10][4];
    #pragma unroll
    for (int c = 0; c < 8; ++c) {
        const float4 v = *(const float4*)(Eb + (size_t)c * HWPIX);
        x[c][0] = v.x; x[c][1] = v.y; x[c][2] = v.z; x[c][3] = v.w;
    }
    #pragma unroll
    for (int j = 0; j < 4; ++j) {
        x[8][j] = (w + j + 0.5f) * (1.0f / 256.0f) - cx;
        x[9][j] = (h + 0.5f) * (1.0f / 256.0f) - cy;
    }

    float y[8][4];
    #pragma unroll
    for (int o = 0; o < 8; ++o) {
        const float bias = th[80 + o];
        float a[4] = {bias, bias, bias, bias};
        #pragma unroll
        for (int i = 0; i < 10; ++i) {
            const float wv = th[o * 10 + i];
            #pragma unroll
            for (int j = 0; j < 4; ++j) a[j] = fmaf(wv, x[i][j], a[j]);
        }
        #pragma unroll
        for (int j = 0; j < 4; ++j) y[o][j] = gelu_fast(a[j]);
    }

    float z[8][4];
    #pragma unroll
    for (int o = 0; o < 8; ++o) {
        const float bias = th[152 + o];
        float a[4] = {bias, bias, bias, bias};
        #pragma unroll
        for (int i = 0; i < 8; ++i) {
            const float wv = th[88 + o * 8 + i];
            #pragma unroll
            for (int j = 0; j < 4; ++j) a[j] = fmaf(wv, y[i][j], a[j]);
        }
        #pragma unroll
        for (int j = 0; j < 4; ++j) z[o][j] = gelu_fast(a[j]);
    }

    const float b2 = th[168];
    float r[4] = {b2, b2, b2, b2};
    #pragma unroll
    for (int i = 0; i < 8; ++i) {
        const float wv = th[160 + i];
        #pragma unroll
        for (int j = 0; j < 4; ++j) r[j] = fmaf(wv, z[i][j], r[j]);
    }

    float4 o4;
    o4.x = r[0]; o4.y = r[1]; o4.z = r[2]; o4.w = r[3];
    *(float4*)(out + (size_t)m * HWPIX + p0) = o4;
}

extern "C" void kernel_launch(void* const* d_in, const int* in_sizes, int n_in,
                              void* d_out, int out_size, void* d_ws, size_t ws_size,
                              hipStream_t stream) {
    const float* E       = (const float*)d_in[0];
    const float* theta   = (const float*)d_in[1];
    const float* centers = (const float*)d_in[2];
    const int*   bidx    = (const int*)d_in[3];
    float* out = (float*)d_out;

    if (ws_size >= (size_t)TPK_BYTES && d_ws != nullptr) {
        uint32_t* tpk = (uint32_t*)d_ws;
        hipLaunchKernelGGL(pack_theta, dim3(NMATCH), dim3(96), 0, stream,
                           theta, tpk);
        hipLaunchKernelGGL(dmh_kernel_dot2, dim3(NMATCH * 64), dim3(256), 0, stream,
                           E, tpk, centers, bidx, out);
    } else {
        hipLaunchKernelGGL(dmh_kernel_f32, dim3(NMATCH * 64), dim3(256), 0, stream,
                           E, theta, centers, bidx, out);
    }
}

// Round 3
// 187.362 us; speedup vs baseline: 1.0059x; 1.0059x over previous
//
#include <hip/hip_runtime.h>
#include <math.h>

// Problem constants: B=8, D=8 (channels), H=256, W=256, M=256
#define HWPIX 65536   // 256*256
#define NMATCH 256
#define THETA_LEN 169
#define TPK_STRIDE 128          // u32 per match in packed-theta workspace
#define TPK_BYTES (NMATCH * TPK_STRIDE * 4)

// __fp16 ext vector: element type of __builtin_amdgcn_cvt_pkrtz's return and
// __builtin_amdgcn_fdot2's operands.
typedef __fp16 half2v __attribute__((ext_vector_type(2)));

// tanh-approx GELU in sigmoid form on HW transcendentals (verified):
//   gelu(x) ~= x * sigmoid(1.5957691x + 0.0713548x^3)
__device__ __forceinline__ float gelu_fast(float v) {
    float t = fmaf(v * v, 0.10294323f, 2.3022082f);
    float e = __builtin_amdgcn_exp2f(-v * t);
    float r = __builtin_amdgcn_rcpf(1.0f + e);
    return v * r;
}

// ---------------------------------------------------------------------------
// Pre-kernel: pack theta (fp32) into per-match fp16 channel-pair weights +
// fp32 biases. Layout per match (u32 indices):
//   [0..39]  L0 weights: o*5+k ; k=0..3 -> (th[o*10+2k], th[o*10+2k+1]),
//                                 k=4   -> (th[o*10+8], th[o*10+9])  (rel pair)
//   [40..47] b0 = th[80+o]      (fp32 bits)
//   [48..79] L1 weights: o*4+k -> (th[88+o*8+2k], th[88+o*8+2k+1])
//   [80..87] b1 = th[152+o]
//   [88..91] L2 weights: k -> (th[160+2k], th[160+2k+1])
//   [92]     b2 = th[168]
// ---------------------------------------------------------------------------
__global__ __launch_bounds__(96) void pack_theta(
    const float* __restrict__ theta, uint32_t* __restrict__ tpk)
{
    const int m = blockIdx.x;
    const int t = threadIdx.x;
    const float* __restrict__ th = theta + m * THETA_LEN;
    uint32_t* __restrict__ o = tpk + m * TPK_STRIDE;

    float a = 0.f, b = 0.f;
    bool isPack = true;
    if (t < 40) {
        int oo = t / 5, k = t % 5;
        if (k < 4) { a = th[oo * 10 + 2 * k]; b = th[oo * 10 + 2 * k + 1]; }
        else       { a = th[oo * 10 + 8];     b = th[oo * 10 + 9]; }
    } else if (t < 48) { isPack = false; a = th[80 + (t - 40)]; }
    else if (t < 80) {
        int oo = (t - 48) / 4, k = (t - 48) % 4;
        a = th[88 + oo * 8 + 2 * k]; b = th[88 + oo * 8 + 2 * k + 1];
    } else if (t < 88) { isPack = false; a = th[152 + (t - 80)]; }
    else if (t < 92) { int k = t - 88; a = th[160 + 2 * k]; b = th[160 + 2 * k + 1]; }
    else if (t == 92) { isPack = false; a = th[168]; }
    else return;

    uint32_t r;
    if (isPack) {
        half2v h = __builtin_amdgcn_cvt_pkrtz(a, b);
        r = __builtin_bit_cast(uint32_t, h);
    } else {
        r = __builtin_bit_cast(uint32_t, a);
    }
    o[t] = r;
}

// ---------------------------------------------------------------------------
// Main kernel (fp16-dot2 path): matmuls via v_dot2_f32_f16 (2 MACs/instr,
// fp32 accumulate). Weights read through a uniform const float* with
// compile-time-constant indices — the exact pattern the fp32 kernel used,
// which the compiler promotes to s_load/SGPR. Bit-casts are register-level
// (__builtin_bit_cast), no memory round-trip, so promotion is not blocked.
// ---------------------------------------------------------------------------
__global__ __launch_bounds__(256) void dmh_kernel_dot2(
    const float* __restrict__ E,        // (8, 8, 256, 256)
    const float* __restrict__ tpkf,     // packed theta (workspace), float view
    const float* __restrict__ centers,  // (256, 2)
    const int*   __restrict__ bidx,     // (256,)
    float* __restrict__ out)            // (256, 256, 256)
{
    const int m    = blockIdx.x >> 6;
    const int tile = blockIdx.x & 63;
    const int p0   = tile * 1024 + threadIdx.x * 4;

    const float* __restrict__ tp = tpkf + (size_t)m * TPK_STRIDE; // uniform
    const float cx = centers[2 * m];
    const float cy = centers[2 * m + 1];
    const int   b  = bidx[m];
    const float* __restrict__ Eb = E + (size_t)b * (8 * HWPIX) + p0;

    const int h = p0 >> 8;
    const int w = p0 & 255;   // multiple of 4 -> 4 pixels share h

    // Inputs packed as channel-pairs: xp[cp][j], cp=0..3 E pairs, cp=4 = (rx,ry)
    half2v xp[5][4];
    #pragma unroll
    for (int cp = 0; cp < 4; ++cp) {
        const float4 v0 = *(const float4*)(Eb + (size_t)(2 * cp) * HWPIX);
        const float4 v1 = *(const float4*)(Eb + (size_t)(2 * cp + 1) * HWPIX);
        xp[cp][0] = __builtin_amdgcn_cvt_pkrtz(v0.x, v1.x);
        xp[cp][1] = __builtin_amdgcn_cvt_pkrtz(v0.y, v1.y);
        xp[cp][2] = __builtin_amdgcn_cvt_pkrtz(v0.z, v1.z);
        xp[cp][3] = __builtin_amdgcn_cvt_pkrtz(v0.w, v1.w);
    }
    const float ry = (h + 0.5f) * (1.0f / 256.0f) - cy;
    #pragma unroll
    for (int j = 0; j < 4; ++j) {
        const float rx = (w + j + 0.5f) * (1.0f / 256.0f) - cx;
        xp[4][j] = __builtin_amdgcn_cvt_pkrtz(rx, ry);
    }

    // Layer 0: 10 -> 8 (5 dot2 per output-pixel)
    float yv[8][4];
    #pragma unroll
    for (int o = 0; o < 8; ++o) {
        const float bias = tp[40 + o];
        float a[4] = {bias, bias, bias, bias};
        #pragma unroll
        for (int k = 0; k < 5; ++k) {
            const half2v wv = __builtin_bit_cast(half2v, tp[o * 5 + k]); // SGPR
            #pragma unroll
            for (int j = 0; j < 4; ++j)
                a[j] = __builtin_amdgcn_fdot2(wv, xp[k][j], a[j], false);
        }
        #pragma unroll
        for (int j = 0; j < 4; ++j) yv[o][j] = gelu_fast(a[j]);
    }
    half2v yp[4][4];
    #pragma unroll
    for (int cp = 0; cp < 4; ++cp)
        #pragma unroll
        for (int j = 0; j < 4; ++j)
            yp[cp][j] = __builtin_amdgcn_cvt_pkrtz(yv[2 * cp][j], yv[2 * cp + 1][j]);

    // Layer 1: 8 -> 8 (4 dot2 per output-pixel)
    float zv[8][4];
    #pragma unroll
    for (int o = 0; o < 8; ++o) {
        const float bias = tp[80 + o];
        float a[4] = {bias, bias, bias, bias};
        #pragma unroll
        for (int k = 0; k < 4; ++k) {
            const half2v wv = __builtin_bit_cast(half2v, tp[48 + o * 4 + k]);
            #pragma unroll
            for (int j = 0; j < 4; ++j)
                a[j] = __builtin_amdgcn_fdot2(wv, yp[k][j], a[j], false);
        }
        #pragma unroll
        for (int j = 0; j < 4; ++j) zv[o][j] = gelu_fast(a[j]);
    }
    half2v zp[4][4];
    #pragma unroll
    for (int cp = 0; cp < 4; ++cp)
        #pragma unroll
        for (int j = 0; j < 4; ++j)
            zp[cp][j] = __builtin_amdgcn_cvt_pkrtz(zv[2 * cp][j], zv[2 * cp + 1][j]);

    // Layer 2: 8 -> 1
    const float b2 = tp[92];
    float r[4] = {b2, b2, b2, b2};
    #pragma unroll
    for (int k = 0; k < 4; ++k) {
        const half2v wv = __builtin_bit_cast(half2v, tp[88 + k]);
        #pragma unroll
        for (int j = 0; j < 4; ++j)
            r[j] = __builtin_amdgcn_fdot2(wv, zp[k][j], r[j], false);
    }

    float4 o4;
    o4.x = r[0]; o4.y = r[1]; o4.z = r[2]; o4.w = r[3];
    *(float4*)(out + (size_t)m * HWPIX + p0) = o4;
}

// ---------------------------------------------------------------------------
// Fallback: verified fp32 kernel (used only if workspace too small).
// ---------------------------------------------------------------------------
__global__ __launch_bounds__(256) void dmh_kernel_f32(
    const float* __restrict__ E,
    const float* __restrict__ theta,
    const float* __restrict__ centers,
    const int*   __restrict__ bidx,
    float* __restrict__ out)
{
    const int m    = blockIdx.x >> 6;
    const int tile = blockIdx.x & 63;
    const int p0   = tile * 1024 + threadIdx.x * 4;

    const float* __restrict__ th = theta + m * THETA_LEN;
    const float cx = centers[2 * m];
    const float cy = centers[2 * m + 1];
    const int   b  = bidx[m];
    const float* __restrict__ Eb = E + (size_t)b * (8 * HWPIX) + p0;

    const int h = p0 >> 8;
    const int w = p0 & 255;

    float x[10][4];
    #pragma unroll
    for (int c = 0; c < 8; ++c) {
        const float4 v = *(const float4*)(Eb + (size_t)c * HWPIX);
        x[c][0] = v.x; x[c][1] = v.y; x[c][2] = v.z; x[c][3] = v.w;
    }
    #pragma unroll
    for (int j = 0; j < 4; ++j) {
        x[8][j] = (w + j + 0.5f) * (1.0f / 256.0f) - cx;
        x[9][j] = (h + 0.5f) * (1.0f / 256.0f) - cy;
    }

    float y[8][4];
    #pragma unroll
    for (int o = 0; o < 8; ++o) {
        const float bias = th[80 + o];
        float a[4] = {bias, bias, bias, bias};
        #pragma unroll
        for (int i = 0; i < 10; ++i) {
            const float wv = th[o * 10 + i];
            #pragma unroll
            for (int j = 0; j < 4; ++j) a[j] = fmaf(wv, x[i][j], a[j]);
        }
        #pragma unroll
        for (int j = 0; j < 4; ++j) y[o][j] = gelu_fast(a[j]);
    }

    float z[8][4];
    #pragma unroll
    for (int o = 0; o < 8; ++o) {
        const float bias = th[152 + o];
        float a[4] = {bias, bias, bias, bias};
        #pragma unroll
        for (int i = 0; i < 8; ++i) {
            const float wv = th[88 + o * 8 + i];
            #pragma unroll
            for (int j = 0; j < 4; ++j) a[j] = fmaf(wv, y[i][j], a[j]);
        }
        #pragma unroll
        for (int j = 0; j < 4; ++j) z[o][j] = gelu_fast(a[j]);
    }

    const float b2 = th[168];
    float r[4] = {b2, b2, b2, b2};
    #pragma unroll
    for (int i = 0; i < 8; ++i) {
        const float wv = th[160 + i];
        #pragma unroll
        for (int j = 0; j < 4; ++j) r[j] = fmaf(wv, z[i][j], r[j]);
    }

    float4 o4;
    o4.x = r[0]; o4.y = r[1]; o4.z = r[2]; o4.w = r[3];
    *(float4*)(out + (size_t)m * HWPIX + p0) = o4;
}

extern "C" void kernel_launch(void* const* d_in, const int* in_sizes, int n_in,
                              void* d_out, int out_size, void* d_ws, size_t ws_size,
                              hipStream_t stream) {
    const float* E       = (const float*)d_in[0];
    const float* theta   = (const float*)d_in[1];
    const float* centers = (const float*)d_in[2];
    const int*   bidx    = (const int*)d_in[3];
    float* out = (float*)d_out;

    if (ws_size >= (size_t)TPK_BYTES && d_ws != nullptr) {
        uint32_t* tpk = (uint32_t*)d_ws;
        hipLaunchKernelGGL(pack_theta, dim3(NMATCH), dim3(96), 0, stream,
                           theta, tpk);
        hipLaunchKernelGGL(dmh_kernel_dot2, dim3(NMATCH * 64), dim3(256), 0, stream,
                           E, (const float*)tpk, centers, bidx, out);
    } else {
        hipLaunchKernelGGL(dmh_kernel_f32, dim3(NMATCH * 64), dim3(256), 0, stream,
                           E, theta, centers, bidx, out);
    }
}